// Round 4
// baseline (193.240 us; speedup 1.0000x reference)
//
#include <hip/hip_runtime.h>

#define CC 192
#define NN 16384
#define TN 32
#define XST 98    // Xs stride: 49 dw (odd) -> conflict-free b64 writes / b128 reads
#define SST 34    // Ss/Vs stride: 17 dw (odd) -> conflict-free b128 reads
#define QXST 104  // kq Xs stride
#define QST 200   // kq SsT stride

typedef unsigned short u16;
typedef __attribute__((ext_vector_type(4))) float f32x4;
typedef __attribute__((ext_vector_type(8))) __bf16 bf16x8;
typedef __attribute__((ext_vector_type(8))) u16 u16x8;
typedef __attribute__((ext_vector_type(4))) u16 u16x4;

union FragU { u16x8 u; bf16x8 b; };

__device__ __forceinline__ u16 f2bf(float f) {
  union { float f; unsigned u; } x; x.f = f;
  return (u16)((x.u + 0x7FFFu + ((x.u >> 16) & 1u)) >> 16);  // RNE
}
__device__ __forceinline__ float bf2f(u16 h) {
  union { unsigned u; float f; } x; x.u = ((unsigned)h) << 16;
  return x.f;
}

// ---------------- kv: K/V projections + ctx partials, 4 blocks/CU ----------------
// Per block: 2 token tiles of TN=32. Per tile: K-proj (2 hf rounds) -> exp/Ss/ksum;
// V-proj (2 hf rounds) -> Vs; wave-private ctx MFMA (K=32, one k-step).
// Ss/Vs rows are wave-owned; cross-wave reads feed only masked (dv>=24 | d>=24)
// outputs, so no barrier is needed around them.
__global__ __launch_bounds__(256, 4)
void kv(const float* __restrict__ k, const float* __restrict__ v,
        const u16* __restrict__ Wb, const float* __restrict__ bk,
        const float* __restrict__ bv, float* __restrict__ part)
{
  __shared__ __align__(16) u16 Xs[TN][XST];        // 6.27 KB
  __shared__ __align__(16) u16 SV[2][192][SST];    // 26.1 KB ([0]=Ss, [1]=Vs; Cs at end)

  const int b = blockIdx.y, blk = blockIdx.x;      // blk 0..255
  const int tid = threadIdx.x;
  const int lg = (tid >> 4) & 3, lc = tid & 15;
  const int wave = tid >> 6, e0 = wave * 48;
  const int g = tid >> 5, sn = tid & 31;

  const float* xb[2] = { k + (size_t)b * CC * NN, v + (size_t)b * CC * NN };
  const u16* Wp[2] = { Wb + 36864, Wb + 2 * 36864 };

  f32x4 acc[3][2];
  f32x4 cacc[2][2][2];
  float ksum_r[3][4];
#pragma unroll
  for (int hi = 0; hi < 2; ++hi)
#pragma unroll
    for (int mt = 0; mt < 2; ++mt)
#pragma unroll
      for (int nt = 0; nt < 2; ++nt) cacc[hi][mt][nt] = f32x4{0.f, 0.f, 0.f, 0.f};
#pragma unroll
  for (int et = 0; et < 3; ++et)
#pragma unroll
    for (int r = 0; r < 4; ++r) ksum_r[et][r] = 0.f;

  for (int t = 0; t < 2; ++t) {
    const int t0 = (blk * 2 + t) * TN;
#pragma unroll
    for (int pj = 0; pj < 2; ++pj) {
#pragma unroll
      for (int et = 0; et < 3; ++et)
#pragma unroll
        for (int nt = 0; nt < 2; ++nt) acc[et][nt] = f32x4{0.f, 0.f, 0.f, 0.f};

#pragma unroll
      for (int hf = 0; hf < 2; ++hf) {
        // ---- stage 96 channels x 32 tokens, transposed, fp32->bf16 ----
#pragma unroll
        for (int i = 0; i < 3; ++i) {
          const int cl = g * 4 + i * 32;
          const float* src = xb[pj] + (size_t)(hf * 96 + cl) * NN + t0 + sn;
          u16x4 pk;
          pk[0] = f2bf(src[0]);
          pk[1] = f2bf(src[NN]);
          pk[2] = f2bf(src[2 * NN]);
          pk[3] = f2bf(src[3 * NN]);
          *reinterpret_cast<u16x4*>(&Xs[sn][cl]) = pk;
        }
        __syncthreads();
        // ---- MFMA: W A-frags straight from global (L2-hot), B-frags from Xs ----
#pragma unroll
        for (int ks = 0; ks < 3; ++ks) {
          FragU a[3], bb[2];
#pragma unroll
          for (int et = 0; et < 3; ++et)
            a[et].u = *reinterpret_cast<const u16x8*>(
                &Wp[pj][(e0 + et * 16 + lc) * 192 + hf * 96 + ks * 32 + lg * 8]);
#pragma unroll
          for (int nt = 0; nt < 2; ++nt)
            bb[nt].u = *reinterpret_cast<const u16x8*>(&Xs[nt * 16 + lc][ks * 32 + lg * 8]);
#pragma unroll
          for (int et = 0; et < 3; ++et)
#pragma unroll
            for (int nt = 0; nt < 2; ++nt)
              acc[et][nt] = __builtin_amdgcn_mfma_f32_16x16x32_bf16(a[et].b, bb[nt].b,
                                                                   acc[et][nt], 0, 0, 0);
        }
        __syncthreads();
      }

      if (pj == 0) {
        // ---- K epilogue: exp -> Ss, token-sum -> ksum_r ----
#pragma unroll
        for (int et = 0; et < 3; ++et)
#pragma unroll
          for (int r = 0; r < 4; ++r) {
            const int e = e0 + et * 16 + lg * 4 + r;
            const float bias = bk[e];
            float sum = 0.f;
#pragma unroll
            for (int nt = 0; nt < 2; ++nt) {
              const float val = __expf(acc[et][nt][r] + bias);
              SV[0][e][nt * 16 + lc] = f2bf(val);
              sum += val;
            }
            sum += __shfl_xor(sum, 1);
            sum += __shfl_xor(sum, 2);
            sum += __shfl_xor(sum, 4);
            sum += __shfl_xor(sum, 8);
            ksum_r[et][r] += sum;
          }
      } else {
        // ---- V epilogue -> Vs; wave-private ctx MFMA (one K=32 step) ----
#pragma unroll
        for (int et = 0; et < 3; ++et)
#pragma unroll
          for (int r = 0; r < 4; ++r) {
            const int e = e0 + et * 16 + lg * 4 + r;
            const float bias = bv[e];
#pragma unroll
            for (int nt = 0; nt < 2; ++nt)
              SV[1][e][nt * 16 + lc] = f2bf(acc[et][nt][r] + bias);
          }
#pragma unroll
        for (int hi = 0; hi < 2; ++hi) {
          const int base = (wave * 2 + hi) * 24;
          FragU av[2], bs[2];
#pragma unroll
          for (int mt = 0; mt < 2; ++mt) {
            int row = base + mt * 16 + lc;   // rows >= base+24 feed masked outputs
            if (row > 191) row = 191;
            av[mt].u = *reinterpret_cast<const u16x8*>(&SV[1][row][lg * 8]);
            bs[mt].u = *reinterpret_cast<const u16x8*>(&SV[0][row][lg * 8]);
          }
#pragma unroll
          for (int mt = 0; mt < 2; ++mt)
#pragma unroll
            for (int nt = 0; nt < 2; ++nt)
              cacc[hi][mt][nt] = __builtin_amdgcn_mfma_f32_16x16x32_bf16(
                  av[mt].b, bs[nt].b, cacc[hi][mt][nt], 0, 0, 0);
        }
      }
    }
  }

  // ---- finale: dense coalesced partial store via LDS bounce (reuse SV as Cs) ----
  __syncthreads();                        // all waves done with SV reads
  float* Cs = (float*)&SV[0][0][0];       // 4800 floats = 19.2 KB <= 26.1 KB
#pragma unroll
  for (int hi = 0; hi < 2; ++hi)
#pragma unroll
    for (int mt = 0; mt < 2; ++mt)
#pragma unroll
      for (int nt = 0; nt < 2; ++nt)
#pragma unroll
        for (int r = 0; r < 4; ++r) {
          const int dv = mt * 16 + lg * 4 + r;
          const int d = nt * 16 + lc;
          if (dv < 24 && d < 24)
            Cs[(wave * 2 + hi) * 576 + dv * 24 + d] = cacc[hi][mt][nt][r];
        }
  if (lc == 0) {
#pragma unroll
    for (int et = 0; et < 3; ++et)
#pragma unroll
      for (int r = 0; r < 4; ++r) {
        const int e = e0 + et * 16 + lg * 4 + r;
        Cs[4608 + e] = ksum_r[et][r];
      }
  }
  __syncthreads();
  const size_t pb = (size_t)(b * 256 + blk) * 4800;
#pragma unroll
  for (int rr = 0; rr < 19; ++rr) {
    const int idx = rr * 256 + tid;
    if (idx < 4800) part[pb + idx] = Cs[idx];
  }
}

// Stage-1 reduce: 16 partials -> 1.  part[1024][4800] -> part2[64][4800]
__global__ void kr1(const float* __restrict__ part, float* __restrict__ part2)
{
  const int idx = blockIdx.x * 256 + threadIdx.x;   // grid.x = 19
  if (idx >= 4800) return;
  const int gy = blockIdx.y;                        // 0..63 (16 groups per batch)
  float s = 0.f;
#pragma unroll
  for (int j = 0; j < 16; ++j)
    s += part[(size_t)(gy * 16 + j) * 4800 + idx];
  part2[(size_t)gy * 4800 + idx] = s;
}

// Stage-2 reduce + normalize: ctx[b][h][d][dv] = sum(ctx_num) / sum(ksum)
__global__ void kr2(const float* __restrict__ part2, float* __restrict__ ctx)
{
  const int id = blockIdx.x * 256 + threadIdx.x;
  if (id >= 4 * 4608) return;
  const int b = id / 4608, r = id % 4608;
  const int h = r / 576, rem = r % 576;
  const int dv = rem / 24, d = rem % 24;
  float s1 = 0.f, s2 = 0.f;
#pragma unroll
  for (int j = 0; j < 16; ++j) {
    const float* pp = part2 + (size_t)(b * 16 + j) * 4800;
    s1 += pp[h * 576 + dv * 24 + d];
    s2 += pp[4608 + h * 24 + d];
  }
  ctx[((b * 8 + h) * 24 + d) * 24 + dv] = s1 / s2;
}

// Meff[b][o][h*24+d] = sum_dv Wo[o][h*24+dv] * ctx[b][h][d][dv]
__global__ void km(const float* __restrict__ Wo, const float* __restrict__ ctx,
                   u16* __restrict__ Meff)
{
  const int o = blockIdx.x, b = blockIdx.y, j = threadIdx.x;
  const int h = j / 24, d = j % 24;
  const float* Wrow = Wo + o * 192 + h * 24;
  const float* crow = ctx + ((b * 8 + h) * 24 + d) * 24;
  float acc = 0.f;
#pragma unroll
  for (int dv = 0; dv < 24; ++dv) acc += Wrow[dv] * crow[dv];
  Meff[(b * 192 + o) * 192 + j] = f2bf(acc);
}

// One 192x192 (W) @ 192x64 (x fp32->bf16) GEMM for kq.
__device__ __forceinline__ void gemm_stage_compute(
    const float* __restrict__ xb, const u16* __restrict__ Wp,
    int t0, int tid, f32x4 acc[3][4], u16 (*Xs)[QXST])
{
  const int lg = (tid >> 4) & 3, lc = tid & 15;
  const int wave = tid >> 6, e0 = wave * 48;
  const int sn = tid & 63, scg = tid >> 6;
#pragma unroll
  for (int et = 0; et < 3; ++et)
#pragma unroll
    for (int nt = 0; nt < 4; ++nt)
      acc[et][nt] = f32x4{0.f, 0.f, 0.f, 0.f};

#pragma unroll
  for (int hf = 0; hf < 2; ++hf) {
#pragma unroll
    for (int i = 0; i < 6; ++i) {
      int cl = scg * 4 + i * 16;
      const float* src = xb + (size_t)(hf * 96 + cl) * NN + t0 + sn;
      u16x4 p;
      p[0] = f2bf(src[0]);
      p[1] = f2bf(src[NN]);
      p[2] = f2bf(src[2 * NN]);
      p[3] = f2bf(src[3 * NN]);
      *reinterpret_cast<u16x4*>(&Xs[sn][cl]) = p;
    }
    __syncthreads();
#pragma unroll
    for (int ks = 0; ks < 3; ++ks) {
      FragU a[3], bb[4];
#pragma unroll
      for (int et = 0; et < 3; ++et)
        a[et].u = *reinterpret_cast<const u16x8*>(
            &Wp[(e0 + et * 16 + lc) * 192 + hf * 96 + ks * 32 + lg * 8]);
#pragma unroll
      for (int nt = 0; nt < 4; ++nt)
        bb[nt].u = *reinterpret_cast<const u16x8*>(&Xs[nt * 16 + lc][ks * 32 + lg * 8]);
#pragma unroll
      for (int et = 0; et < 3; ++et)
#pragma unroll
        for (int nt = 0; nt < 4; ++nt)
          acc[et][nt] = __builtin_amdgcn_mfma_f32_16x16x32_bf16(a[et].b, bb[nt].b,
                                                               acc[et][nt], 0, 0, 0);
    }
    __syncthreads();
  }
}

// Q kernel: q-proj -> SsT[n][e] -> softmax over d -> Meff GEMM -> out (+bo).
__global__ __launch_bounds__(256, 4)
void kq(const float* __restrict__ q, const u16* __restrict__ Wb,
        const float* __restrict__ bq, const u16* __restrict__ Meff,
        const float* __restrict__ bo, float* __restrict__ out)
{
  __shared__ __align__(16) u16 Xs[64][QXST];
  __shared__ __align__(16) u16 SsT[64][QST];

  const int b = blockIdx.y;
  const int t0 = blockIdx.x * 64;
  const int tid = threadIdx.x;
  const int lg = (tid >> 4) & 3, lc = tid & 15;
  const int wave = tid >> 6, e0 = wave * 48;
  const u16* Mb = Meff + b * 36864;

  f32x4 acc[3][4];

  gemm_stage_compute(q + (size_t)b * CC * NN, Wb, t0, tid, acc, Xs);
#pragma unroll
  for (int et = 0; et < 3; ++et)
#pragma unroll
    for (int r = 0; r < 4; ++r) {
      int e = e0 + et * 16 + lg * 4 + r;
      float bias = bq[e];
#pragma unroll
      for (int nt = 0; nt < 4; ++nt)
        SsT[nt * 16 + lc][e] = f2bf(acc[et][nt][r] + bias);
    }
  __syncthreads();

#pragma unroll
  for (int ii = 0; ii < 2; ++ii) {
    const int item = ii * 256 + tid;
    const int n = item & 63, h = item >> 6;
    u16* rowp = &SsT[n][h * 24];
    float vals[24];
    float m = -1e30f;
#pragma unroll
    for (int d = 0; d < 24; ++d) {
      vals[d] = bf2f(rowp[d]);
      m = fmaxf(m, vals[d]);
    }
    float s = 0.f;
#pragma unroll
    for (int d = 0; d < 24; ++d) { vals[d] = __expf(vals[d] - m); s += vals[d]; }
    const float inv = 1.f / s;
#pragma unroll
    for (int d = 0; d < 24; ++d) rowp[d] = f2bf(vals[d] * inv);
  }
  __syncthreads();

#pragma unroll
  for (int et = 0; et < 3; ++et)
#pragma unroll
    for (int nt = 0; nt < 4; ++nt) acc[et][nt] = f32x4{0.f, 0.f, 0.f, 0.f};
#pragma unroll
  for (int ks = 0; ks < 6; ++ks) {
    FragU a[3], bb[4];
#pragma unroll
    for (int et = 0; et < 3; ++et)
      a[et].u = *reinterpret_cast<const u16x8*>(
          &Mb[(e0 + et * 16 + lc) * 192 + ks * 32 + lg * 8]);
#pragma unroll
    for (int nt = 0; nt < 4; ++nt)
      bb[nt].u = *reinterpret_cast<const u16x8*>(&SsT[nt * 16 + lc][ks * 32 + lg * 8]);
#pragma unroll
    for (int et = 0; et < 3; ++et)
#pragma unroll
      for (int nt = 0; nt < 4; ++nt)
        acc[et][nt] = __builtin_amdgcn_mfma_f32_16x16x32_bf16(a[et].b, bb[nt].b,
                                                             acc[et][nt], 0, 0, 0);
  }

#pragma unroll
  for (int et = 0; et < 3; ++et)
#pragma unroll
    for (int r = 0; r < 4; ++r) {
      int row = e0 + et * 16 + lg * 4 + r;
      float bias = bo[row];
#pragma unroll
      for (int nt = 0; nt < 4; ++nt)
        out[(size_t)(b * 192 + row) * NN + t0 + nt * 16 + lc] = acc[et][nt][r] + bias;
    }
}

// Convert Wq/Wk/Wv to bf16 (packed [3][192][192]).
__global__ void kz(const float* __restrict__ Wq, const float* __restrict__ Wk,
                   const float* __restrict__ Wv, u16* __restrict__ Wb)
{
  const int i = blockIdx.x * 256 + threadIdx.x;
  if (i < 110592) {
    const float* src = (i < 36864) ? Wq : (i < 73728) ? Wk : Wv;
    Wb[i] = f2bf(src[i % 36864]);
  }
}

extern "C" void kernel_launch(void* const* d_in, const int* in_sizes, int n_in,
                              void* d_out, int out_size, void* d_ws, size_t ws_size,
                              hipStream_t stream)
{
  const float* q  = (const float*)d_in[0];
  const float* k  = (const float*)d_in[1];
  const float* v  = (const float*)d_in[2];
  const float* Wq = (const float*)d_in[3];
  const float* bq = (const float*)d_in[4];
  const float* Wk = (const float*)d_in[5];
  const float* bk = (const float*)d_in[6];
  const float* Wv = (const float*)d_in[7];
  const float* bv = (const float*)d_in[8];
  const float* Wo = (const float*)d_in[9];
  const float* bo = (const float*)d_in[10];
  float* out = (float*)d_out;

  // workspace carve (256B-aligned); total ~21.5 MB
  char* w = (char*)d_ws;
  u16*   Wb    = (u16*)(w);                    // 221184 B : [3][192][192] bf16
  float* part  = (float*)(w + 221184);         // 19660800 B : [1024][4800]
  float* part2 = (float*)(w + 19881984);       // 1228800 B : [64][4800]
  float* ctx   = (float*)(w + 21110784);       // 73728 B : [4][8][24][24]
  u16*   Meff  = (u16*)(w + 21184512);         // 294912 B : [4][192][192] bf16

  hipLaunchKernelGGL(kz, dim3(432), dim3(256), 0, stream, Wq, Wk, Wv, Wb);
  hipLaunchKernelGGL(kv, dim3(256, 4), dim3(256), 0, stream, k, v, Wb, bk, bv, part);
  hipLaunchKernelGGL(kr1, dim3(19, 64), dim3(256), 0, stream, part, part2);
  hipLaunchKernelGGL(kr2, dim3(72), dim3(256), 0, stream, part2, ctx);
  hipLaunchKernelGGL(km, dim3(192, 4), dim3(192), 0, stream, Wo, ctx, Meff);
  hipLaunchKernelGGL(kq, dim3(256, 4), dim3(256), 0, stream, q, Wb, bq, Meff, bo, out);
}

// Round 5
// 137.213 us; speedup vs baseline: 1.4083x; 1.4083x over previous
//
#include <hip/hip_runtime.h>

#define CC 192
#define NN 16384
#define TN 32
#define XST 98    // Xs stride: 49 dw (odd) -> conflict-free b64 writes / b128 reads
#define SST 34    // Ss/Vs stride: 17 dw (odd) -> conflict-free b128 reads
#define QXST 104  // kq Xs stride
#define QST 200   // kq SsT stride

typedef unsigned short u16;
typedef __attribute__((ext_vector_type(4))) float f32x4;
typedef __attribute__((ext_vector_type(8))) __bf16 bf16x8;
typedef __attribute__((ext_vector_type(8))) u16 u16x8;
typedef __attribute__((ext_vector_type(4))) u16 u16x4;

union FragU { u16x8 u; bf16x8 b; };

__device__ __forceinline__ u16 f2bf(float f) {
  union { float f; unsigned u; } x; x.f = f;
  return (u16)((x.u + 0x7FFFu + ((x.u >> 16) & 1u)) >> 16);  // RNE
}
__device__ __forceinline__ float bf2f(u16 h) {
  union { unsigned u; float f; } x; x.u = ((unsigned)h) << 16;
  return x.f;
}

// ---------------- kv: K/V projections + ctx partials ----------------
// Per block: 2 token tiles of TN=32. Per tile: K-proj (2 hf rounds) -> exp/Ss/ksum;
// V-proj (2 hf rounds) -> Vs; wave-private ctx MFMA (K=32, one k-step).
// Ss/Vs rows are wave-owned; cross-wave reads feed only masked (dv>=24 | d>=24)
// outputs, so no barrier is needed around them.
// NOTE: __launch_bounds__(256,2) — empirically hipcc caps VGPR at 128 here and
// does NOT spill; (256,4) capped at 64 and spilled ~380MB of scratch (R4).
__global__ __launch_bounds__(256, 2)
void kv(const float* __restrict__ k, const float* __restrict__ v,
        const u16* __restrict__ Wb, const float* __restrict__ bk,
        const float* __restrict__ bv, float* __restrict__ part)
{
  __shared__ __align__(16) u16 Xs[TN][XST];        // 6.27 KB
  __shared__ __align__(16) u16 SV[2][192][SST];    // 26.1 KB ([0]=Ss, [1]=Vs; Cs at end)

  const int b = blockIdx.y, blk = blockIdx.x;      // blk 0..255
  const int tid = threadIdx.x;
  const int lg = (tid >> 4) & 3, lc = tid & 15;
  const int wave = tid >> 6, e0 = wave * 48;
  const int g = tid >> 5, sn = tid & 31;

  const float* xb[2] = { k + (size_t)b * CC * NN, v + (size_t)b * CC * NN };
  const u16* Wp[2] = { Wb + 36864, Wb + 2 * 36864 };

  f32x4 acc[3][2];
  f32x4 cacc[2][2][2];
  float ksum_r[3][4];
#pragma unroll
  for (int hi = 0; hi < 2; ++hi)
#pragma unroll
    for (int mt = 0; mt < 2; ++mt)
#pragma unroll
      for (int nt = 0; nt < 2; ++nt) cacc[hi][mt][nt] = f32x4{0.f, 0.f, 0.f, 0.f};
#pragma unroll
  for (int et = 0; et < 3; ++et)
#pragma unroll
    for (int r = 0; r < 4; ++r) ksum_r[et][r] = 0.f;

  for (int t = 0; t < 2; ++t) {
    const int t0 = (blk * 2 + t) * TN;
#pragma unroll
    for (int pj = 0; pj < 2; ++pj) {
#pragma unroll
      for (int et = 0; et < 3; ++et)
#pragma unroll
        for (int nt = 0; nt < 2; ++nt) acc[et][nt] = f32x4{0.f, 0.f, 0.f, 0.f};

#pragma unroll
      for (int hf = 0; hf < 2; ++hf) {
        // ---- stage 96 channels x 32 tokens, transposed, fp32->bf16 ----
#pragma unroll
        for (int i = 0; i < 3; ++i) {
          const int cl = g * 4 + i * 32;
          const float* src = xb[pj] + (size_t)(hf * 96 + cl) * NN + t0 + sn;
          u16x4 pk;
          pk[0] = f2bf(src[0]);
          pk[1] = f2bf(src[NN]);
          pk[2] = f2bf(src[2 * NN]);
          pk[3] = f2bf(src[3 * NN]);
          *reinterpret_cast<u16x4*>(&Xs[sn][cl]) = pk;
        }
        __syncthreads();
        // ---- MFMA: W A-frags from global (L2-hot), B-frags from Xs ----
#pragma unroll
        for (int ks = 0; ks < 3; ++ks) {
          FragU a[3], bb[2];
#pragma unroll
          for (int et = 0; et < 3; ++et)
            a[et].u = *reinterpret_cast<const u16x8*>(
                &Wp[pj][(e0 + et * 16 + lc) * 192 + hf * 96 + ks * 32 + lg * 8]);
#pragma unroll
          for (int nt = 0; nt < 2; ++nt)
            bb[nt].u = *reinterpret_cast<const u16x8*>(&Xs[nt * 16 + lc][ks * 32 + lg * 8]);
#pragma unroll
          for (int et = 0; et < 3; ++et)
#pragma unroll
            for (int nt = 0; nt < 2; ++nt)
              acc[et][nt] = __builtin_amdgcn_mfma_f32_16x16x32_bf16(a[et].b, bb[nt].b,
                                                                   acc[et][nt], 0, 0, 0);
        }
        __syncthreads();
      }

      if (pj == 0) {
        // ---- K epilogue: exp -> Ss, token-sum -> ksum_r ----
#pragma unroll
        for (int et = 0; et < 3; ++et)
#pragma unroll
          for (int r = 0; r < 4; ++r) {
            const int e = e0 + et * 16 + lg * 4 + r;
            const float bias = bk[e];
            float sum = 0.f;
#pragma unroll
            for (int nt = 0; nt < 2; ++nt) {
              const float val = __expf(acc[et][nt][r] + bias);
              SV[0][e][nt * 16 + lc] = f2bf(val);
              sum += val;
            }
            sum += __shfl_xor(sum, 1);
            sum += __shfl_xor(sum, 2);
            sum += __shfl_xor(sum, 4);
            sum += __shfl_xor(sum, 8);
            ksum_r[et][r] += sum;
          }
      } else {
        // ---- V epilogue -> Vs; wave-private ctx MFMA (one K=32 step) ----
#pragma unroll
        for (int et = 0; et < 3; ++et)
#pragma unroll
          for (int r = 0; r < 4; ++r) {
            const int e = e0 + et * 16 + lg * 4 + r;
            const float bias = bv[e];
#pragma unroll
            for (int nt = 0; nt < 2; ++nt)
              SV[1][e][nt * 16 + lc] = f2bf(acc[et][nt][r] + bias);
          }
#pragma unroll
        for (int hi = 0; hi < 2; ++hi) {
          const int base = (wave * 2 + hi) * 24;
          FragU av[2], bs[2];
#pragma unroll
          for (int mt = 0; mt < 2; ++mt) {
            int row = base + mt * 16 + lc;   // rows >= base+24 feed masked outputs
            if (row > 191) row = 191;
            av[mt].u = *reinterpret_cast<const u16x8*>(&SV[1][row][lg * 8]);
            bs[mt].u = *reinterpret_cast<const u16x8*>(&SV[0][row][lg * 8]);
          }
#pragma unroll
          for (int mt = 0; mt < 2; ++mt)
#pragma unroll
            for (int nt = 0; nt < 2; ++nt)
              cacc[hi][mt][nt] = __builtin_amdgcn_mfma_f32_16x16x32_bf16(
                  av[mt].b, bs[nt].b, cacc[hi][mt][nt], 0, 0, 0);
        }
      }
    }
  }

  // ---- finale: dense coalesced partial store via LDS bounce (reuse SV as Cs) ----
  __syncthreads();                        // all waves done with SV reads
  float* Cs = (float*)&SV[0][0][0];       // 4800 floats = 19.2 KB <= 26.1 KB
#pragma unroll
  for (int hi = 0; hi < 2; ++hi)
#pragma unroll
    for (int mt = 0; mt < 2; ++mt)
#pragma unroll
      for (int nt = 0; nt < 2; ++nt)
#pragma unroll
        for (int r = 0; r < 4; ++r) {
          const int dv = mt * 16 + lg * 4 + r;
          const int d = nt * 16 + lc;
          if (dv < 24 && d < 24)
            Cs[(wave * 2 + hi) * 576 + dv * 24 + d] = cacc[hi][mt][nt][r];
        }
  if (lc == 0) {
#pragma unroll
    for (int et = 0; et < 3; ++et)
#pragma unroll
      for (int r = 0; r < 4; ++r) {
        const int e = e0 + et * 16 + lg * 4 + r;
        Cs[4608 + e] = ksum_r[et][r];
      }
  }
  __syncthreads();
  const size_t pb = (size_t)(b * 256 + blk) * 4800;
#pragma unroll
  for (int rr = 0; rr < 19; ++rr) {
    const int idx = rr * 256 + tid;
    if (idx < 4800) part[pb + idx] = Cs[idx];
  }
}

// Stage-1 reduce: 16 partials -> 1.  part[1024][4800] -> part2[64][4800]
__global__ void kr1(const float* __restrict__ part, float* __restrict__ part2)
{
  const int idx = blockIdx.x * 256 + threadIdx.x;   // grid.x = 19
  if (idx >= 4800) return;
  const int gy = blockIdx.y;                        // 0..63 (16 groups per batch)
  float s = 0.f;
#pragma unroll
  for (int j = 0; j < 16; ++j)
    s += part[(size_t)(gy * 16 + j) * 4800 + idx];
  part2[(size_t)gy * 4800 + idx] = s;
}

// Stage-2 reduce + normalize: ctx[b][h][d][dv] = sum(ctx_num) / sum(ksum)
__global__ void kr2(const float* __restrict__ part2, float* __restrict__ ctx)
{
  const int id = blockIdx.x * 256 + threadIdx.x;
  if (id >= 4 * 4608) return;
  const int b = id / 4608, r = id % 4608;
  const int h = r / 576, rem = r % 576;
  const int dv = rem / 24, d = rem % 24;
  float s1 = 0.f, s2 = 0.f;
#pragma unroll
  for (int j = 0; j < 16; ++j) {
    const float* pp = part2 + (size_t)(b * 16 + j) * 4800;
    s1 += pp[h * 576 + dv * 24 + d];
    s2 += pp[4608 + h * 24 + d];
  }
  ctx[((b * 8 + h) * 24 + d) * 24 + dv] = s1 / s2;
}

// Meff[b][o][h*24+d] = sum_dv Wo[o][h*24+dv] * ctx[b][h][d][dv]
__global__ void km(const float* __restrict__ Wo, const float* __restrict__ ctx,
                   u16* __restrict__ Meff)
{
  const int o = blockIdx.x, b = blockIdx.y, j = threadIdx.x;
  const int h = j / 24, d = j % 24;
  const float* Wrow = Wo + o * 192 + h * 24;
  const float* crow = ctx + ((b * 8 + h) * 24 + d) * 24;
  float acc = 0.f;
#pragma unroll
  for (int dv = 0; dv < 24; ++dv) acc += Wrow[dv] * crow[dv];
  Meff[(b * 192 + o) * 192 + j] = f2bf(acc);
}

// One 192x192 (W) @ 192x64 (x fp32->bf16) GEMM for kq.
__device__ __forceinline__ void gemm_stage_compute(
    const float* __restrict__ xb, const u16* __restrict__ Wp,
    int t0, int tid, f32x4 acc[3][4], u16 (*Xs)[QXST])
{
  const int lg = (tid >> 4) & 3, lc = tid & 15;
  const int wave = tid >> 6, e0 = wave * 48;
  const int sn = tid & 63, scg = tid >> 6;
#pragma unroll
  for (int et = 0; et < 3; ++et)
#pragma unroll
    for (int nt = 0; nt < 4; ++nt)
      acc[et][nt] = f32x4{0.f, 0.f, 0.f, 0.f};

#pragma unroll
  for (int hf = 0; hf < 2; ++hf) {
#pragma unroll
    for (int i = 0; i < 6; ++i) {
      int cl = scg * 4 + i * 16;
      const float* src = xb + (size_t)(hf * 96 + cl) * NN + t0 + sn;
      u16x4 p;
      p[0] = f2bf(src[0]);
      p[1] = f2bf(src[NN]);
      p[2] = f2bf(src[2 * NN]);
      p[3] = f2bf(src[3 * NN]);
      *reinterpret_cast<u16x4*>(&Xs[sn][cl]) = p;
    }
    __syncthreads();
#pragma unroll
    for (int ks = 0; ks < 3; ++ks) {
      FragU a[3], bb[4];
#pragma unroll
      for (int et = 0; et < 3; ++et)
        a[et].u = *reinterpret_cast<const u16x8*>(
            &Wp[(e0 + et * 16 + lc) * 192 + hf * 96 + ks * 32 + lg * 8]);
#pragma unroll
      for (int nt = 0; nt < 4; ++nt)
        bb[nt].u = *reinterpret_cast<const u16x8*>(&Xs[nt * 16 + lc][ks * 32 + lg * 8]);
#pragma unroll
      for (int et = 0; et < 3; ++et)
#pragma unroll
        for (int nt = 0; nt < 4; ++nt)
          acc[et][nt] = __builtin_amdgcn_mfma_f32_16x16x32_bf16(a[et].b, bb[nt].b,
                                                               acc[et][nt], 0, 0, 0);
    }
    __syncthreads();
  }
}

// Q kernel: q-proj -> SsT[n][e] -> softmax over d -> Meff GEMM -> out (+bo).
__global__ __launch_bounds__(256, 2)
void kq(const float* __restrict__ q, const u16* __restrict__ Wb,
        const float* __restrict__ bq, const u16* __restrict__ Meff,
        const float* __restrict__ bo, float* __restrict__ out)
{
  __shared__ __align__(16) u16 Xs[64][QXST];
  __shared__ __align__(16) u16 SsT[64][QST];

  const int b = blockIdx.y;
  const int t0 = blockIdx.x * 64;
  const int tid = threadIdx.x;
  const int lg = (tid >> 4) & 3, lc = tid & 15;
  const int wave = tid >> 6, e0 = wave * 48;
  const u16* Mb = Meff + b * 36864;

  f32x4 acc[3][4];

  gemm_stage_compute(q + (size_t)b * CC * NN, Wb, t0, tid, acc, Xs);
#pragma unroll
  for (int et = 0; et < 3; ++et)
#pragma unroll
    for (int r = 0; r < 4; ++r) {
      int e = e0 + et * 16 + lg * 4 + r;
      float bias = bq[e];
#pragma unroll
      for (int nt = 0; nt < 4; ++nt)
        SsT[nt * 16 + lc][e] = f2bf(acc[et][nt][r] + bias);
    }
  __syncthreads();

#pragma unroll
  for (int ii = 0; ii < 2; ++ii) {
    const int item = ii * 256 + tid;
    const int n = item & 63, h = item >> 6;
    u16* rowp = &SsT[n][h * 24];
    float vals[24];
    float m = -1e30f;
#pragma unroll
    for (int d = 0; d < 24; ++d) {
      vals[d] = bf2f(rowp[d]);
      m = fmaxf(m, vals[d]);
    }
    float s = 0.f;
#pragma unroll
    for (int d = 0; d < 24; ++d) { vals[d] = __expf(vals[d] - m); s += vals[d]; }
    const float inv = 1.f / s;
#pragma unroll
    for (int d = 0; d < 24; ++d) rowp[d] = f2bf(vals[d] * inv);
  }
  __syncthreads();

#pragma unroll
  for (int et = 0; et < 3; ++et)
#pragma unroll
    for (int nt = 0; nt < 4; ++nt) acc[et][nt] = f32x4{0.f, 0.f, 0.f, 0.f};
#pragma unroll
  for (int ks = 0; ks < 6; ++ks) {
    FragU a[3], bb[4];
#pragma unroll
    for (int et = 0; et < 3; ++et)
      a[et].u = *reinterpret_cast<const u16x8*>(
          &Mb[(e0 + et * 16 + lc) * 192 + ks * 32 + lg * 8]);
#pragma unroll
    for (int nt = 0; nt < 4; ++nt)
      bb[nt].u = *reinterpret_cast<const u16x8*>(&SsT[nt * 16 + lc][ks * 32 + lg * 8]);
#pragma unroll
    for (int et = 0; et < 3; ++et)
#pragma unroll
      for (int nt = 0; nt < 4; ++nt)
        acc[et][nt] = __builtin_amdgcn_mfma_f32_16x16x32_bf16(a[et].b, bb[nt].b,
                                                             acc[et][nt], 0, 0, 0);
  }

#pragma unroll
  for (int et = 0; et < 3; ++et)
#pragma unroll
    for (int r = 0; r < 4; ++r) {
      int row = e0 + et * 16 + lg * 4 + r;
      float bias = bo[row];
#pragma unroll
      for (int nt = 0; nt < 4; ++nt)
        out[(size_t)(b * 192 + row) * NN + t0 + nt * 16 + lc] = acc[et][nt][r] + bias;
    }
}

// Convert Wq/Wk/Wv to bf16 (packed [3][192][192]).
__global__ void kz(const float* __restrict__ Wq, const float* __restrict__ Wk,
                   const float* __restrict__ Wv, u16* __restrict__ Wb)
{
  const int i = blockIdx.x * 256 + threadIdx.x;
  if (i < 110592) {
    const float* src = (i < 36864) ? Wq : (i < 73728) ? Wk : Wv;
    Wb[i] = f2bf(src[i % 36864]);
  }
}

extern "C" void kernel_launch(void* const* d_in, const int* in_sizes, int n_in,
                              void* d_out, int out_size, void* d_ws, size_t ws_size,
                              hipStream_t stream)
{
  const float* q  = (const float*)d_in[0];
  const float* k  = (const float*)d_in[1];
  const float* v  = (const float*)d_in[2];
  const float* Wq = (const float*)d_in[3];
  const float* bq = (const float*)d_in[4];
  const float* Wk = (const float*)d_in[5];
  const float* bk = (const float*)d_in[6];
  const float* Wv = (const float*)d_in[7];
  const float* bv = (const float*)d_in[8];
  const float* Wo = (const float*)d_in[9];
  const float* bo = (const float*)d_in[10];
  float* out = (float*)d_out;

  // workspace carve (256B-aligned); total ~21.5 MB
  char* w = (char*)d_ws;
  u16*   Wb    = (u16*)(w);                    // 221184 B : [3][192][192] bf16
  float* part  = (float*)(w + 221184);         // 19660800 B : [1024][4800]
  float* part2 = (float*)(w + 19881984);       // 1228800 B : [64][4800]
  float* ctx   = (float*)(w + 21110784);       // 73728 B : [4][8][24][24]
  u16*   Meff  = (u16*)(w + 21184512);         // 294912 B : [4][192][192] bf16

  hipLaunchKernelGGL(kz, dim3(432), dim3(256), 0, stream, Wq, Wk, Wv, Wb);
  hipLaunchKernelGGL(kv, dim3(256, 4), dim3(256), 0, stream, k, v, Wb, bk, bv, part);
  hipLaunchKernelGGL(kr1, dim3(19, 64), dim3(256), 0, stream, part, part2);
  hipLaunchKernelGGL(kr2, dim3(72), dim3(256), 0, stream, part2, ctx);
  hipLaunchKernelGGL(km, dim3(192, 4), dim3(192), 0, stream, Wo, ctx, Meff);
  hipLaunchKernelGGL(kq, dim3(256, 4), dim3(256), 0, stream, q, Wb, bq, Meff, bo, out);
}